// Round 9
// baseline (2263.161 us; speedup 1.0000x reference)
//
#include <hip/hip_runtime.h>

// Wave-level LDS ordering fence: waits all outstanding LDS ops; "memory"
// clobber stops compiler reordering LDS accesses across it. Waves are fully
// independent (per-wave LDS slots) -> no barriers needed.
#define FENCE() asm volatile("s_waitcnt lgkmcnt(0)" ::: "memory")

typedef float v2f   __attribute__((ext_vector_type(2)));
typedef float f32x4 __attribute__((ext_vector_type(4)));

__device__ __forceinline__ float fshfl_xor(float v, int m) {
  return __shfl_xor(v, m, 64);
}
// Raw single-instruction approx ops (~1e-7 rel err): fine for rotation params.
__device__ __forceinline__ float fsqrt(float x) { return __builtin_amdgcn_sqrtf(x); }
__device__ __forceinline__ float frcp (float x) { return __builtin_amdgcn_rcpf(x); }
__device__ __forceinline__ float frsq (float x) { return __builtin_amdgcn_rsqf(x); }
__device__ __forceinline__ v2f   fma2(v2f a, v2f b, v2f c)       { return __builtin_elementwise_fma(a, b, c); }
__device__ __forceinline__ f32x4 fma4(f32x4 a, f32x4 b, f32x4 c) { return __builtin_elementwise_fma(a, b, c); }

// One block = 256 threads = 4 waves, one 32x32 SPD matrix per wave.
// r9 = r8 with the Pt stride bug fixed: Pt is [16][32+pad] (stride 34), NOT
// [16][20]. Pt lives in the dead upper half of Cc (Cc+576): the Ps pass
// finishes all its Cc column reads (wave-lockstep) before the Pt stores, and
// M2 only writes Cc[0..285]. Slot shrinks to 1184 floats ->
// LDS 18944 B/block -> 8 blocks/CU (32 waves/CU, HW max).
#define PT_S 34
__global__ __launch_bounds__(256, 8) void spd_fused(
    const float* __restrict__ xg,
    const float* __restrict__ w1g,
    const float* __restrict__ w2g,
    const float* __restrict__ w3g,
    const float* __restrict__ fcg,
    float* __restrict__ outg,
    int B)
{
  __shared__ float slot[4][1184];

  const int tid  = threadIdx.x;
  const int wid  = tid >> 6;
  const int lane = tid & 63;

  float* Cc  = slot[wid];          // 1152: x (stride 32) -> M1 cols (stride 36) -> M2/V2 (stride 18)
  float* Pt  = slot[wid] + 576;    // 544: Ps transposed [16][PT_S] (in dead Cc space)
  float* scr = slot[wid] + 1152;   // 20:  stage-3 J + loglam

  const long b = (long)blockIdx.x * 4 + wid;
  if (b >= B) return;

  // ---------------- load x -> Cc row-major [32][32] (stride 32)
  {
    const f32x4* xv = (const f32x4*)(xg + (size_t)b * 1024);
    f32x4* c4 = (f32x4*)Cc;
    #pragma unroll
    for (int jj = 0; jj < 4; ++jj) {
      int i4 = lane + 64 * jj;
      c4[i4] = xv[i4];
    }
  }
  FENCE();

  const int j = lane & 31;
  const int h = lane >> 5;

  // ---------------- Tmat = x * w1 in registers (packed). T2[e2] = rows
  // {16h+2e2, +1} of column j. Uses x symmetry: read x rows as f32x4.
  v2f T2[8];
  {
    #pragma unroll
    for (int e = 0; e < 8; ++e) T2[e] = (v2f){0.f, 0.f};
    const f32x4* c4 = (const f32x4*)Cc;
    #pragma unroll 4
    for (int c = 0; c < 32; ++c) {
      float wv = w1g[c * 32 + j];
      v2f wv2 = {wv, wv};
      f32x4 x0 = c4[c * 8 + h * 4 + 0];
      f32x4 x1 = c4[c * 8 + h * 4 + 1];
      f32x4 x2 = c4[c * 8 + h * 4 + 2];
      f32x4 x3 = c4[c * 8 + h * 4 + 3];
      T2[0] = fma2(x0.lo, wv2, T2[0]); T2[1] = fma2(x0.hi, wv2, T2[1]);
      T2[2] = fma2(x1.lo, wv2, T2[2]); T2[3] = fma2(x1.hi, wv2, T2[3]);
      T2[4] = fma2(x2.lo, wv2, T2[4]); T2[5] = fma2(x2.hi, wv2, T2[5]);
      T2[6] = fma2(x3.lo, wv2, T2[6]); T2[7] = fma2(x3.hi, wv2, T2[7]);
    }
  }
  FENCE();   // all x reads complete before M1 overwrites Cc

  // ---------------- M1 = w1^T * Tmat -> Cc linear column-major, stride 36.
  // Outer product over r (r = 16h+e on this lane), halves via shfl_xor(32).
  {
    const f32x4* w14 = (const f32x4*)w1g;   // row r = w14[r*8 + 0..7]
    #pragma unroll
    for (int ih2 = 0; ih2 < 4; ++ih2) {     // output rows 8*ih2 .. 8*ih2+7
      f32x4 A = {0.f, 0.f, 0.f, 0.f};
      f32x4 Bv = {0.f, 0.f, 0.f, 0.f};
      #pragma unroll 4
      for (int e = 0; e < 16; ++e) {
        int r = 16 * h + e;
        float tv = T2[e >> 1][e & 1];
        f32x4 tv4 = {tv, tv, tv, tv};
        A  = fma4(w14[r * 8 + ih2 * 2],     tv4, A);
        Bv = fma4(w14[r * 8 + ih2 * 2 + 1], tv4, Bv);
      }
      float av[8] = {A.x, A.y, A.z, A.w, Bv.x, Bv.y, Bv.z, Bv.w};
      #pragma unroll
      for (int u = 0; u < 8; ++u) av[u] += fshfl_xor(av[u], 32);
      if (h == (ih2 & 1)) {
        *(f32x4*)(Cc + j * 36 + ih2 * 8)     = (f32x4){av[0], av[1], av[2], av[3]};
        *(f32x4*)(Cc + j * 36 + ih2 * 8 + 4) = (f32x4){av[4], av[5], av[6], av[7]};
      }
    }
  }
  FENCE();

  // ---------------- one-sided Jacobi, n=32 (16 pairs/round, 4 lanes/pair)
  {
    const int g4 = lane >> 2;
    const int rb = (lane & 3) << 3;   // this lane handles rows rb..rb+7
    const int p_init = (g4 == 0) ? 31 : g4;
    const int q_init = (g4 == 0) ? 0  : 31 - g4;
    #pragma unroll 1
    for (int sweep = 0; sweep < 8; ++sweep) {
      float offmax = 0.f;
      int p = p_init, q = q_init;
      #pragma unroll 1
      for (int r = 0; r < 31; ++r) {
        const int pa = p * 36 + rb;
        const int qa = q * 36 + rb;
        f32x4 a0 = *(const f32x4*)(Cc + pa);
        f32x4 a1 = *(const f32x4*)(Cc + pa + 4);
        f32x4 b0 = *(const f32x4*)(Cc + qa);
        f32x4 b1 = *(const f32x4*)(Cc + qa + 4);
        v2f s2a = a0.lo * a0.lo;
        s2a = fma2(a0.hi, a0.hi, s2a); s2a = fma2(a1.lo, a1.lo, s2a); s2a = fma2(a1.hi, a1.hi, s2a);
        v2f s2b = b0.lo * b0.lo;
        s2b = fma2(b0.hi, b0.hi, s2b); s2b = fma2(b1.lo, b1.lo, s2b); s2b = fma2(b1.hi, b1.hi, s2b);
        v2f s2g = a0.lo * b0.lo;
        s2g = fma2(a0.hi, b0.hi, s2g); s2g = fma2(a1.lo, b1.lo, s2g); s2g = fma2(a1.hi, b1.hi, s2g);
        float sa = s2a.x + s2a.y;
        float sb = s2b.x + s2b.y;
        float sg = s2g.x + s2g.y;
        sa += fshfl_xor(sa, 1); sb += fshfl_xor(sb, 1); sg += fshfl_xor(sg, 1);
        sa += fshfl_xor(sa, 2); sb += fshfl_xor(sb, 2); sg += fshfl_xor(sg, 2);
        float rel = sg * sg * frcp(fmaxf(sa * sb, 1e-30f));
        offmax = fmaxf(offmax, rel);
        if (rel > 1e-13f) {
          float u  = 0.5f * (sb - sa);
          float R  = fsqrt(u * u + sg * sg);
          float t  = sg * frcp(u + ((u >= 0.f) ? R : -R));
          float ct = frsq(1.f + t * t);
          float st = ct * t;
          f32x4 n0 = a0 * ct - b0 * st;
          f32x4 n1 = a1 * ct - b1 * st;
          f32x4 m0 = a0 * st + b0 * ct;
          f32x4 m1 = a1 * st + b1 * ct;
          *(f32x4*)(Cc + pa)     = n0;
          *(f32x4*)(Cc + pa + 4) = n1;
          *(f32x4*)(Cc + qa)     = m0;
          *(f32x4*)(Cc + qa + 4) = m1;
        }
        FENCE();
        p = (g4 == 0) ? 31 : ((p == 30) ? 0 : p + 1);
        q = (q == 30) ? 0 : q + 1;
      }
      #pragma unroll
      for (int m = 1; m <= 32; m <<= 1) offmax = fmaxf(offmax, fshfl_xor(offmax, m));
      if (offmax < 1e-11f) break;
    }
  }

  // ---------------- lambda_1 + ReEig + Ps = sqrt(clamp(lam1))*v1hat^T w2,
  // single fused pass; Ps written TRANSPOSED -> Pt[16][PT_S] (= Cc+576).
  // Safe overlap: wave-lockstep means all lanes issue their last Cc read
  // before any lane issues the first Pt store; compiler keeps order for
  // may-alias LDS accesses.
  {
    const int k1 = lane & 31;            // column owned by this lane
    const int jb = (lane >> 5) << 3;     // cols jb..jb+7 of w2
    f32x4 accA = {0.f, 0.f, 0.f, 0.f};
    f32x4 accB = {0.f, 0.f, 0.f, 0.f};
    v2f ssv = {0.f, 0.f};
    #pragma unroll 2
    for (int t = 0; t < 8; ++t) {
      f32x4 v = *(const f32x4*)(Cc + k1 * 36 + (t << 2));
      ssv = fma2(v.lo, v.lo, ssv);
      ssv = fma2(v.hi, v.hi, ssv);
      const int r0 = t << 2;
      #pragma unroll
      for (int s = 0; s < 4; ++s) {
        float vs = v[s];
        f32x4 vs4 = {vs, vs, vs, vs};
        accA = fma4(*(const f32x4*)(w2g + (r0 + s) * 16 + jb),     vs4, accA);
        accB = fma4(*(const f32x4*)(w2g + (r0 + s) * 16 + jb + 4), vs4, accB);
      }
    }
    float ss  = ssv.x + ssv.y;
    float lam = fsqrt(ss);
    float sc1 = (lam > 0.f) ? (fsqrt(fmaxf(lam, 1e-4f)) * frcp(lam)) : 0.f;
    accA = accA * sc1;
    accB = accB * sc1;
    #pragma unroll
    for (int u = 0; u < 8; ++u)
      Pt[(jb + u) * PT_S + k1] = (u < 4) ? accA[u] : accB[u - 4];
  }
  FENCE();

  // ---------------- M2 = Ps^T Ps -> Cc col-major (stride 18), via Pt b128s.
  // (reads Pt @ Cc[576..1117], writes Cc[0..285] -- disjoint)
  {
    const int i0 = lane >> 4;     // 0..3
    const int j2 = lane & 15;
    v2f acc0 = {0.f,0.f}, acc1 = {0.f,0.f}, acc2 = {0.f,0.f}, acc3 = {0.f,0.f};
    #pragma unroll 2
    for (int kk = 0; kk < 32; kk += 4) {
      f32x4 a4 = *(const f32x4*)(Pt + j2 * PT_S + kk);
      f32x4 b0 = *(const f32x4*)(Pt + (i0     ) * PT_S + kk);
      f32x4 b1 = *(const f32x4*)(Pt + (4  + i0) * PT_S + kk);
      f32x4 b2 = *(const f32x4*)(Pt + (8  + i0) * PT_S + kk);
      f32x4 b3 = *(const f32x4*)(Pt + (12 + i0) * PT_S + kk);
      acc0 = fma2(a4.lo, b0.lo, acc0); acc0 = fma2(a4.hi, b0.hi, acc0);
      acc1 = fma2(a4.lo, b1.lo, acc1); acc1 = fma2(a4.hi, b1.hi, acc1);
      acc2 = fma2(a4.lo, b2.lo, acc2); acc2 = fma2(a4.hi, b2.hi, acc2);
      acc3 = fma2(a4.lo, b3.lo, acc3); acc3 = fma2(a4.hi, b3.hi, acc3);
    }
    Cc[j2 * 18 + i0]      = acc0.x + acc0.y;
    Cc[j2 * 18 + 4  + i0] = acc1.x + acc1.y;
    Cc[j2 * 18 + 8  + i0] = acc2.x + acc2.y;
    Cc[j2 * 18 + 12 + i0] = acc3.x + acc3.y;
  }
  FENCE();

  // ---------------- one-sided Jacobi, n=16 (8 pairs/round, 8 lanes/pair)
  {
    const int g8 = lane >> 3;
    const int rb = (lane & 7) * 2;
    const int p_init = (g8 == 0) ? 15 : g8;
    const int q_init = (g8 == 0) ? 0  : 15 - g8;
    #pragma unroll 1
    for (int sweep = 0; sweep < 6; ++sweep) {
      float offmax = 0.f;
      int p = p_init, q = q_init;
      #pragma unroll 1
      for (int r = 0; r < 15; ++r) {
        v2f av = *(const v2f*)(Cc + p * 18 + rb);
        v2f cv = *(const v2f*)(Cc + q * 18 + rb);
        v2f pa2 = av * av;
        v2f pc2 = cv * cv;
        v2f pg2 = av * cv;
        float sa = pa2.x + pa2.y;
        float sb = pc2.x + pc2.y;
        float sg = pg2.x + pg2.y;
        sa += fshfl_xor(sa, 1); sb += fshfl_xor(sb, 1); sg += fshfl_xor(sg, 1);
        sa += fshfl_xor(sa, 2); sb += fshfl_xor(sb, 2); sg += fshfl_xor(sg, 2);
        sa += fshfl_xor(sa, 4); sb += fshfl_xor(sb, 4); sg += fshfl_xor(sg, 4);
        float rel = sg * sg * frcp(fmaxf(sa * sb, 1e-30f));
        offmax = fmaxf(offmax, rel);
        if (rel > 1e-13f) {
          float u  = 0.5f * (sb - sa);
          float R  = fsqrt(u * u + sg * sg);
          float t  = sg * frcp(u + ((u >= 0.f) ? R : -R));
          float ct = frsq(1.f + t * t);
          float st = ct * t;
          v2f nv = av * ct - cv * st;
          v2f mv = av * st + cv * ct;
          *(v2f*)(Cc + p * 18 + rb) = nv;
          *(v2f*)(Cc + q * 18 + rb) = mv;
        }
        FENCE();
        p = (g8 == 0) ? 15 : ((p == 14) ? 0 : p + 1);
        q = (q == 14) ? 0 : q + 1;
      }
      #pragma unroll
      for (int m = 1; m <= 32; m <<= 1) offmax = fmaxf(offmax, fshfl_xor(offmax, m));
      if (offmax < 1e-11f) break;
    }
  }

  // ---------------- Qb[k][j] = (V2^T w3)[k][j] * sqrt(clamp(lam2_k)) in regs
  float qv;
  const int kq = lane >> 2;
  const int jq = lane & 3;
  {
    v2f aq = {0.f, 0.f}, sq = {0.f, 0.f};
    #pragma unroll 4
    for (int t = 0; t < 8; ++t) {
      v2f v  = *(const v2f*)(Cc + kq * 18 + 2 * t);
      v2f wp = { w3g[(2 * t) * 4 + jq], w3g[(2 * t + 1) * 4 + jq] };
      aq = fma2(v, wp, aq);
      sq = fma2(v, v, sq);
    }
    float accq = aq.x + aq.y;
    float ss   = sq.x + sq.y;
    float lam = fsqrt(ss);
    float scl = (lam > 0.f) ? (frcp(lam) * fsqrt(fmaxf(lam, 1e-4f))) : 0.f;
    qv = accq * scl;
  }

  // ---------------- stage 3: one-sided Jacobi ON THE 16x4 FACTOR, with
  // accumulated rotations J (eigenvectors of M3 = Q^T Q). 5 sweeps.
  float jv = (kq == jq) ? 1.f : 0.f;
  {
    #define ROT3(P_, Q_) do {                                             \
      float w_ = fshfl_xor(qv, (P_) ^ (Q_));                              \
      float s1 = qv * qv, s2 = w_ * w_, s3 = qv * w_;                     \
      s1 += fshfl_xor(s1, 4);  s2 += fshfl_xor(s2, 4);  s3 += fshfl_xor(s3, 4);  \
      s1 += fshfl_xor(s1, 8);  s2 += fshfl_xor(s2, 8);  s3 += fshfl_xor(s3, 8);  \
      s1 += fshfl_xor(s1, 16); s2 += fshfl_xor(s2, 16); s3 += fshfl_xor(s3, 16); \
      s1 += fshfl_xor(s1, 32); s2 += fshfl_xor(s2, 32); s3 += fshfl_xor(s3, 32); \
      bool isp = (jq == (P_)), isq = (jq == (Q_));                        \
      float sa = isp ? s1 : s2;                                           \
      float sb = isp ? s2 : s1;                                           \
      float u_ = 0.5f * (sb - sa);                                        \
      float R_ = fsqrt(u_ * u_ + s3 * s3);                                \
      float dn_ = u_ + copysignf(fmaxf(R_, 1e-30f), u_);                  \
      float t_ = s3 * frcp(dn_);                                          \
      float ct = frsq(1.f + t_ * t_);                                     \
      float st = ct * t_;                                                 \
      float wj_ = fshfl_xor(jv, (P_) ^ (Q_));                             \
      float nv  = isp ? (ct * qv - st * w_)  : (st * w_  + ct * qv);      \
      float nvj = isp ? (ct * jv - st * wj_) : (st * wj_ + ct * jv);      \
      if (isp | isq) { qv = nv; jv = nvj; }                               \
    } while (0)

    #pragma unroll 1
    for (int sweep = 0; sweep < 5; ++sweep) {
      ROT3(0,1); ROT3(2,3); ROT3(0,2); ROT3(1,3); ROT3(0,3); ROT3(1,2);
    }
    #undef ROT3
  }

  // ---------------- lambda_3 = ||col||^2, LogEig via J, FC, log_softmax
  {
    float ss = qv * qv;
    ss += fshfl_xor(ss, 4); ss += fshfl_xor(ss, 8);
    ss += fshfl_xor(ss, 16); ss += fshfl_xor(ss, 32);
    float lwv = logf(fmaxf(ss, 1e-10f));       // log eigenvalue of column jq
    if (kq < 4)  scr[kq * 4 + jq] = jv;        // J, row-major 4x4
    if (kq == 0) scr[16 + jq] = lwv;           // lanes 0..3: per-column loglam
    FENCE();

    float f = 0.f;
    if (lane < 16) {
      int i3 = lane >> 2, j3 = lane & 3;
      #pragma unroll
      for (int c = 0; c < 4; ++c)
        f += scr[16 + c] * scr[i3 * 4 + c] * scr[j3 * 4 + c];
    }
    float t0 = 0.f, t1 = 0.f;
    if (lane < 16) { t0 = f * fcg[2 * lane]; t1 = f * fcg[2 * lane + 1]; }
    t0 += fshfl_xor(t0, 1); t1 += fshfl_xor(t1, 1);
    t0 += fshfl_xor(t0, 2); t1 += fshfl_xor(t1, 2);
    t0 += fshfl_xor(t0, 4); t1 += fshfl_xor(t1, 4);
    t0 += fshfl_xor(t0, 8); t1 += fshfl_xor(t1, 8);
    float mx  = fmaxf(t0, t1);
    float lse = mx + logf(expf(t0 - mx) + expf(t1 - mx));

    float* outFeat = outg + (size_t)B * 2;
    if (lane < 16) outFeat[(size_t)b * 16 + lane] = f;
    if (lane < 2)  outg[(size_t)b * 2 + lane] = (lane == 0 ? t0 : t1) - lse;
  }
}

extern "C" void kernel_launch(void* const* d_in, const int* in_sizes, int n_in,
                              void* d_out, int out_size, void* d_ws, size_t ws_size,
                              hipStream_t stream) {
  const float* x  = (const float*)d_in[0];
  const float* w1 = (const float*)d_in[1];
  const float* w2 = (const float*)d_in[2];
  const float* w3 = (const float*)d_in[3];
  const float* fc = (const float*)d_in[4];
  float* out = (float*)d_out;
  int B = in_sizes[0] / 1024;
  int grid = (B + 3) / 4;
  hipLaunchKernelGGL(spd_fused, dim3(grid), dim3(256), 0, stream,
                     x, w1, w2, w3, fc, out, B);
}

// Round 10
// 2216.559 us; speedup vs baseline: 1.0210x; 1.0210x over previous
//
#include <hip/hip_runtime.h>

// Wave-level LDS ordering fence for the few remaining LDS phase transitions.
#define FENCE() asm volatile("s_waitcnt lgkmcnt(0)" ::: "memory")

typedef float v2f   __attribute__((ext_vector_type(2)));
typedef float f32x4 __attribute__((ext_vector_type(4)));

__device__ __forceinline__ float fshfl_xor(float v, int m) { return __shfl_xor(v, m, 64); }
__device__ __forceinline__ float fshfl(float v, int s)     { return __shfl(v, s, 64); }
__device__ __forceinline__ float fsqrt(float x) { return __builtin_amdgcn_sqrtf(x); }
__device__ __forceinline__ float frcp (float x) { return __builtin_amdgcn_rcpf(x); }
__device__ __forceinline__ float frsq (float x) { return __builtin_amdgcn_rsqf(x); }
__device__ __forceinline__ v2f   fma2(v2f a, v2f b, v2f c)       { return __builtin_elementwise_fma(a, b, c); }
__device__ __forceinline__ f32x4 fma4(f32x4 a, f32x4 b, f32x4 c) { return __builtin_elementwise_fma(a, b, c); }

// One block = 256 threads = 4 waves, one 32x32 SPD matrix per wave.
// r10: REGISTER-RESIDENT Jacobi (r9 was LDS-pipe/fence-bound: occupancy 86%,
// VALU 59%, dur flat). Stage-1: lane c+32h owns rows 16h..16h+15 of column c;
// per round 16 ds_bpermute exchange the partner column, dots+rotation in
// registers, NO LDS read/write/fence in the hot loop. Stage-2 same (4 rows
// per lane). Partner schedule m = (c==N-1)?r : (c==r)?N-1 : (2r-c) mod (N-1)
// reproduces the old tournament; rotation is orientation-invariant, and
// sb (=sum u^2) is bitwise-equal to the partner's sa, so pair-lanes never
// diverge on the skip branch.
// LDS: 4*1152*4 = 18432 B/block -> 8 blocks/CU.
#define PT_S 34
__global__ __launch_bounds__(256, 8) void spd_fused(
    const float* __restrict__ xg,
    const float* __restrict__ w1g,
    const float* __restrict__ w2g,
    const float* __restrict__ w3g,
    const float* __restrict__ fcg,
    float* __restrict__ outg,
    int B)
{
  __shared__ float slot[4][1152];

  const int tid  = threadIdx.x;
  const int wid  = tid >> 6;
  const int lane = tid & 63;

  float* Cc = slot[wid];          // x (stride 32) -> M1 cols (stride 36) -> Qb/J scratch
  float* Pt = slot[wid] + 576;    // Ps transposed [16][PT_S], in dead M1 space

  const long b = (long)blockIdx.x * 4 + wid;
  if (b >= B) return;

  // ---------------- load x -> Cc row-major [32][32] (stride 32)
  {
    const f32x4* xv = (const f32x4*)(xg + (size_t)b * 1024);
    f32x4* c4 = (f32x4*)Cc;
    #pragma unroll
    for (int jj = 0; jj < 4; ++jj) {
      int i4 = lane + 64 * jj;
      c4[i4] = xv[i4];
    }
  }
  FENCE();

  const int j = lane & 31;
  const int h = lane >> 5;

  // ---------------- Tmat = x * w1 in registers (packed). T2[e] = rows
  // {16h+2e, +1} of column j. Uses x symmetry: read x rows as f32x4.
  v2f T2[8];
  {
    #pragma unroll
    for (int e = 0; e < 8; ++e) T2[e] = (v2f){0.f, 0.f};
    const f32x4* c4 = (const f32x4*)Cc;
    #pragma unroll 4
    for (int c = 0; c < 32; ++c) {
      float wv = w1g[c * 32 + j];
      v2f wv2 = {wv, wv};
      f32x4 x0 = c4[c * 8 + h * 4 + 0];
      f32x4 x1 = c4[c * 8 + h * 4 + 1];
      f32x4 x2 = c4[c * 8 + h * 4 + 2];
      f32x4 x3 = c4[c * 8 + h * 4 + 3];
      T2[0] = fma2(x0.lo, wv2, T2[0]); T2[1] = fma2(x0.hi, wv2, T2[1]);
      T2[2] = fma2(x1.lo, wv2, T2[2]); T2[3] = fma2(x1.hi, wv2, T2[3]);
      T2[4] = fma2(x2.lo, wv2, T2[4]); T2[5] = fma2(x2.hi, wv2, T2[5]);
      T2[6] = fma2(x3.lo, wv2, T2[6]); T2[7] = fma2(x3.hi, wv2, T2[7]);
    }
  }
  FENCE();   // all x reads complete before M1 overwrites Cc

  // ---------------- M1 = w1^T * Tmat -> Cc linear column-major, stride 36.
  {
    const f32x4* w14 = (const f32x4*)w1g;   // row r = w14[r*8 + 0..7]
    #pragma unroll
    for (int ih2 = 0; ih2 < 4; ++ih2) {     // output rows 8*ih2 .. 8*ih2+7
      f32x4 A = {0.f, 0.f, 0.f, 0.f};
      f32x4 Bv = {0.f, 0.f, 0.f, 0.f};
      #pragma unroll 4
      for (int e = 0; e < 16; ++e) {
        int r = 16 * h + e;
        float tv = T2[e >> 1][e & 1];
        f32x4 tv4 = {tv, tv, tv, tv};
        A  = fma4(w14[r * 8 + ih2 * 2],     tv4, A);
        Bv = fma4(w14[r * 8 + ih2 * 2 + 1], tv4, Bv);
      }
      float av[8] = {A.x, A.y, A.z, A.w, Bv.x, Bv.y, Bv.z, Bv.w};
      #pragma unroll
      for (int u = 0; u < 8; ++u) av[u] += fshfl_xor(av[u], 32);
      if (h == (ih2 & 1)) {
        *(f32x4*)(Cc + j * 36 + ih2 * 8)     = (f32x4){av[0], av[1], av[2], av[3]};
        *(f32x4*)(Cc + j * 36 + ih2 * 8 + 4) = (f32x4){av[4], av[5], av[6], av[7]};
      }
    }
  }
  FENCE();

  // ---------------- load own column half to registers (one-time)
  alignas(16) float v1r[16];
  {
    const float* bp = Cc + j * 36 + (h << 4);
    *(f32x4*)(v1r)      = *(const f32x4*)(bp);
    *(f32x4*)(v1r + 4)  = *(const f32x4*)(bp + 4);
    *(f32x4*)(v1r + 8)  = *(const f32x4*)(bp + 8);
    *(f32x4*)(v1r + 12) = *(const f32x4*)(bp + 12);
  }

  // ---------------- one-sided Jacobi, n=32, fully register-resident.
  {
    const int hb = lane & 32;     // half bit (0 / 32)
    #pragma unroll 1
    for (int sweep = 0; sweep < 8; ++sweep) {
      float offmax = 0.f;
      #pragma unroll 1
      for (int r = 0; r < 31; ++r) {
        int d = 2 * r - j;
        d += (d >> 31) & 31;
        if (d >= 31) d -= 31;
        const int m = (j == 31) ? r : ((j == r) ? 31 : d);
        const int mlane = m | hb;
        alignas(16) float u[16];
        #pragma unroll
        for (int i = 0; i < 16; ++i) u[i] = fshfl(v1r[i], mlane);
        v2f* pv = (v2f*)v1r;
        v2f* pu = (v2f*)u;
        v2f s2a = {0.f, 0.f}, s2b = {0.f, 0.f}, s2g = {0.f, 0.f};
        #pragma unroll
        for (int i = 0; i < 8; ++i) {
          s2a = fma2(pv[i], pv[i], s2a);
          s2b = fma2(pu[i], pu[i], s2b);
          s2g = fma2(pv[i], pu[i], s2g);
        }
        float sa = s2a.x + s2a.y;
        float sb = s2b.x + s2b.y;
        float sg = s2g.x + s2g.y;
        sa += fshfl_xor(sa, 32);
        sb += fshfl_xor(sb, 32);
        sg += fshfl_xor(sg, 32);
        const bool isp = j < m;
        float nA = isp ? sa : sb;
        float nB = isp ? sb : sa;
        float rel = sg * sg * frcp(fmaxf(nA * nB, 1e-30f));
        offmax = fmaxf(offmax, rel);
        if (rel > 1e-13f) {
          float uu = 0.5f * (nB - nA);
          float R  = fsqrt(uu * uu + sg * sg);
          float t  = sg * frcp(uu + ((uu >= 0.f) ? R : -R));
          float ct = frsq(1.f + t * t);
          float st = ct * t;
          float s  = isp ? -st : st;
          v2f ct2 = {ct, ct}, sv2 = {s, s};
          #pragma unroll
          for (int i = 0; i < 8; ++i)
            pv[i] = fma2(pu[i], sv2, pv[i] * ct2);
        }
      }
      #pragma unroll
      for (int mm = 1; mm <= 32; mm <<= 1) offmax = fmaxf(offmax, fshfl_xor(offmax, mm));
      if (offmax < 1e-11f) break;
    }
  }

  // ---------------- lambda_1 + ReEig + Ps = sqrt(clamp(lam1))*v1hat^T w2,
  // all from registers; Pt[16][PT_S] written transposed (conflict-free).
  {
    v2f* pv = (v2f*)v1r;
    v2f ssv = {0.f, 0.f};
    #pragma unroll
    for (int i = 0; i < 8; ++i) ssv = fma2(pv[i], pv[i], ssv);
    float ss = ssv.x + ssv.y;
    ss += fshfl_xor(ss, 32);
    float lam = fsqrt(ss);
    float sc1 = (lam > 0.f) ? (fsqrt(fmaxf(lam, 1e-4f)) * frcp(lam)) : 0.f;
    f32x4 accq[4];
    #pragma unroll
    for (int t = 0; t < 4; ++t) accq[t] = (f32x4){0.f, 0.f, 0.f, 0.f};
    #pragma unroll 4
    for (int i = 0; i < 16; ++i) {
      int rr = (h << 4) + i;
      float vs = v1r[i];
      f32x4 vs4 = {vs, vs, vs, vs};
      const f32x4* wrow = (const f32x4*)(w2g + rr * 16);
      accq[0] = fma4(wrow[0], vs4, accq[0]);
      accq[1] = fma4(wrow[1], vs4, accq[1]);
      accq[2] = fma4(wrow[2], vs4, accq[2]);
      accq[3] = fma4(wrow[3], vs4, accq[3]);
    }
    float* af = (float*)accq;
    #pragma unroll
    for (int t = 0; t < 16; ++t) af[t] = (af[t] + fshfl_xor(af[t], 32)) * sc1;
    // lane (j,h) stores j-cols 8h..8h+7 of its Ps row (static indices only)
    #pragma unroll
    for (int s = 0; s < 8; ++s) {
      float val = h ? af[8 + s] : af[s];
      int jj = (h << 3) + s;
      Pt[jj * PT_S + j] = val;
    }
  }
  FENCE();

  // ---------------- M2 = Ps^T Ps directly into stage-2 registers.
  // lane = c2 + 16*h4 owns rows 4h4..4h4+3 of M2 column c2.
  const int c2 = lane & 15;
  const int h4 = lane >> 4;
  alignas(16) float v2r[4];
  {
    v2f acc[4];
    #pragma unroll
    for (int e = 0; e < 4; ++e) acc[e] = (v2f){0.f, 0.f};
    #pragma unroll 2
    for (int kk = 0; kk < 32; kk += 4) {
      f32x4 a4 = *(const f32x4*)(Pt + c2 * PT_S + kk);
      #pragma unroll
      for (int e = 0; e < 4; ++e) {
        f32x4 be = *(const f32x4*)(Pt + (4 * h4 + e) * PT_S + kk);
        acc[e] = fma2(a4.lo, be.lo, acc[e]);
        acc[e] = fma2(a4.hi, be.hi, acc[e]);
      }
    }
    #pragma unroll
    for (int e = 0; e < 4; ++e) v2r[e] = acc[e].x + acc[e].y;
  }

  // ---------------- one-sided Jacobi, n=16, register-resident.
  {
    const int h4b = lane & 48;    // h4*16 bits
    #pragma unroll 1
    for (int sweep = 0; sweep < 6; ++sweep) {
      float offmax = 0.f;
      #pragma unroll 1
      for (int r = 0; r < 15; ++r) {
        int d = 2 * r - c2;
        d += (d >> 31) & 15;
        if (d >= 15) d -= 15;
        const int m = (c2 == 15) ? r : ((c2 == r) ? 15 : d);
        const int mlane = m | h4b;
        float u0 = fshfl(v2r[0], mlane);
        float u1 = fshfl(v2r[1], mlane);
        float u2 = fshfl(v2r[2], mlane);
        float u3 = fshfl(v2r[3], mlane);
        v2f va = {v2r[0], v2r[1]}, vb = {v2r[2], v2r[3]};
        v2f ua = {u0, u1},         ub = {u2, u3};
        v2f s2a = fma2(vb, vb, va * va);
        v2f s2b = fma2(ub, ub, ua * ua);
        v2f s2g = fma2(vb, ub, va * ua);
        float sa = s2a.x + s2a.y;
        float sb = s2b.x + s2b.y;
        float sg = s2g.x + s2g.y;
        sa += fshfl_xor(sa, 16); sa += fshfl_xor(sa, 32);
        sb += fshfl_xor(sb, 16); sb += fshfl_xor(sb, 32);
        sg += fshfl_xor(sg, 16); sg += fshfl_xor(sg, 32);
        const bool isp = c2 < m;
        float nA = isp ? sa : sb;
        float nB = isp ? sb : sa;
        float rel = sg * sg * frcp(fmaxf(nA * nB, 1e-30f));
        offmax = fmaxf(offmax, rel);
        if (rel > 1e-13f) {
          float uu = 0.5f * (nB - nA);
          float R  = fsqrt(uu * uu + sg * sg);
          float t  = sg * frcp(uu + ((uu >= 0.f) ? R : -R));
          float ct = frsq(1.f + t * t);
          float st = ct * t;
          float s  = isp ? -st : st;
          v2r[0] = ct * v2r[0] + s * u0;
          v2r[1] = ct * v2r[1] + s * u1;
          v2r[2] = ct * v2r[2] + s * u2;
          v2r[3] = ct * v2r[3] + s * u3;
        }
      }
      #pragma unroll
      for (int mm = 1; mm <= 32; mm <<= 1) offmax = fmaxf(offmax, fshfl_xor(offmax, mm));
      if (offmax < 1e-11f) break;
    }
  }

  // ---------------- Qb row c2 = (V2^T w3)[c2][:] * sqrt(clamp(lam2)) from regs
  {
    f32x4 qq = {0.f, 0.f, 0.f, 0.f};
    float ssp = 0.f;
    #pragma unroll
    for (int e = 0; e < 4; ++e) {
      float vv = v2r[e];
      f32x4 vv4 = {vv, vv, vv, vv};
      qq = fma4(*(const f32x4*)(w3g + (4 * h4 + e) * 4), vv4, qq);
      ssp = __builtin_fmaf(vv, vv, ssp);
    }
    float q0 = qq.x, q1 = qq.y, q2 = qq.z, q3 = qq.w;
    q0 += fshfl_xor(q0, 16); q0 += fshfl_xor(q0, 32);
    q1 += fshfl_xor(q1, 16); q1 += fshfl_xor(q1, 32);
    q2 += fshfl_xor(q2, 16); q2 += fshfl_xor(q2, 32);
    q3 += fshfl_xor(q3, 16); q3 += fshfl_xor(q3, 32);
    ssp += fshfl_xor(ssp, 16); ssp += fshfl_xor(ssp, 32);
    float lam = fsqrt(ssp);
    float scl = (lam > 0.f) ? (frcp(lam) * fsqrt(fmaxf(lam, 1e-4f))) : 0.f;
    if (h4 == 0)
      *(f32x4*)(Cc + c2 * 4) = (f32x4){q0 * scl, q1 * scl, q2 * scl, q3 * scl};
  }
  FENCE();

  // ---------------- stage 3: one-sided Jacobi ON THE 16x4 FACTOR, with
  // accumulated rotations J (eigenvectors of M3 = Q^T Q). 5 sweeps.
  float qv = Cc[lane];            // Qb[kq][jq], kq*4+jq == lane
  const int kq = lane >> 2;
  const int jq = lane & 3;
  float jv = (kq == jq) ? 1.f : 0.f;
  {
    #define ROT3(P_, Q_) do {                                             \
      float w_ = fshfl_xor(qv, (P_) ^ (Q_));                              \
      float s1 = qv * qv, s2 = w_ * w_, s3 = qv * w_;                     \
      s1 += fshfl_xor(s1, 4);  s2 += fshfl_xor(s2, 4);  s3 += fshfl_xor(s3, 4);  \
      s1 += fshfl_xor(s1, 8);  s2 += fshfl_xor(s2, 8);  s3 += fshfl_xor(s3, 8);  \
      s1 += fshfl_xor(s1, 16); s2 += fshfl_xor(s2, 16); s3 += fshfl_xor(s3, 16); \
      s1 += fshfl_xor(s1, 32); s2 += fshfl_xor(s2, 32); s3 += fshfl_xor(s3, 32); \
      bool isp = (jq == (P_)), isq = (jq == (Q_));                        \
      float sa = isp ? s1 : s2;                                           \
      float sb = isp ? s2 : s1;                                           \
      float u_ = 0.5f * (sb - sa);                                        \
      float R_ = fsqrt(u_ * u_ + s3 * s3);                                \
      float dn_ = u_ + copysignf(fmaxf(R_, 1e-30f), u_);                  \
      float t_ = s3 * frcp(dn_);                                          \
      float ct = frsq(1.f + t_ * t_);                                     \
      float st = ct * t_;                                                 \
      float wj_ = fshfl_xor(jv, (P_) ^ (Q_));                             \
      float nv  = isp ? (ct * qv - st * w_)  : (st * w_  + ct * qv);      \
      float nvj = isp ? (ct * jv - st * wj_) : (st * wj_ + ct * jv);      \
      if (isp | isq) { qv = nv; jv = nvj; }                               \
    } while (0)

    #pragma unroll 1
    for (int sweep = 0; sweep < 5; ++sweep) {
      ROT3(0,1); ROT3(2,3); ROT3(0,2); ROT3(1,3); ROT3(0,3); ROT3(1,2);
    }
    #undef ROT3
  }

  // ---------------- lambda_3 = ||col||^2, LogEig via J, FC, log_softmax
  {
    float ss = qv * qv;
    ss += fshfl_xor(ss, 4); ss += fshfl_xor(ss, 8);
    ss += fshfl_xor(ss, 16); ss += fshfl_xor(ss, 32);
    float lwv = logf(fmaxf(ss, 1e-10f));       // log eigenvalue of column jq
    if (kq < 4)  Cc[64 + kq * 4 + jq] = jv;    // J, row-major 4x4
    if (kq == 0) Cc[80 + jq] = lwv;            // lanes 0..3: per-column loglam
    FENCE();

    float f = 0.f;
    if (lane < 16) {
      int i3 = lane >> 2, j3 = lane & 3;
      #pragma unroll
      for (int c = 0; c < 4; ++c)
        f += Cc[80 + c] * Cc[64 + i3 * 4 + c] * Cc[64 + j3 * 4 + c];
    }
    float t0 = 0.f, t1 = 0.f;
    if (lane < 16) { t0 = f * fcg[2 * lane]; t1 = f * fcg[2 * lane + 1]; }
    t0 += fshfl_xor(t0, 1); t1 += fshfl_xor(t1, 1);
    t0 += fshfl_xor(t0, 2); t1 += fshfl_xor(t1, 2);
    t0 += fshfl_xor(t0, 4); t1 += fshfl_xor(t1, 4);
    t0 += fshfl_xor(t0, 8); t1 += fshfl_xor(t1, 8);
    float mx  = fmaxf(t0, t1);
    float lse = mx + logf(expf(t0 - mx) + expf(t1 - mx));

    float* outFeat = outg + (size_t)B * 2;
    if (lane < 16) outFeat[(size_t)b * 16 + lane] = f;
    if (lane < 2)  outg[(size_t)b * 2 + lane] = (lane == 0 ? t0 : t1) - lse;
  }
}

extern "C" void kernel_launch(void* const* d_in, const int* in_sizes, int n_in,
                              void* d_out, int out_size, void* d_ws, size_t ws_size,
                              hipStream_t stream) {
  const float* x  = (const float*)d_in[0];
  const float* w1 = (const float*)d_in[1];
  const float* w2 = (const float*)d_in[2];
  const float* w3 = (const float*)d_in[3];
  const float* fc = (const float*)d_in[4];
  float* out = (float*)d_out;
  int B = in_sizes[0] / 1024;
  int grid = (B + 3) / 4;
  hipLaunchKernelGGL(spd_fused, dim3(grid), dim3(256), 0, stream,
                     x, w1, w2, w3, fc, out, B);
}